// Round 2
// baseline (978.727 us; speedup 1.0000x reference)
//
#include <hip/hip_runtime.h>
#include <hip/hip_cooperative_groups.h>
#include <stdint.h>
#include <stddef.h>

namespace cg = cooperative_groups;

// ---------------- workspace layout (bytes) ----------------
// 0     : uint32 flag (0 = f32 inputs, 1 = bf16 inputs)
// 64    : double F[80]          (FF_FILT[t,b] = F[t*8+b], f64)
// 768   : double trT[8][2048]   (b-major trace0: trT[b*2048+i])
// 131840: double s0[2048]
// 148224: double s1[2048]
#define WS_F_OFF      64
#define WS_TRACE0_OFF 768
#define WS_S0_OFF     131840
#define WS_S1_OFF     148224

// ---------------- threefry2x32 (JAX-exact, 20 rounds) ----------------
__host__ __device__ inline void tf2x32(uint32_t k0, uint32_t k1,
                                       uint32_t& x0, uint32_t& x1) {
  uint32_t ks0 = k0, ks1 = k1, ks2 = k0 ^ k1 ^ 0x1BD11BDAu;
  x0 += ks0; x1 += ks1;
#define TF_ROT(v, n) (((v) << (n)) | ((v) >> (32 - (n))))
#define TF_R(r) { x0 += x1; x1 = TF_ROT(x1, r); x1 ^= x0; }
  TF_R(13) TF_R(15) TF_R(26) TF_R(6)   x0 += ks1; x1 += ks2 + 1u;
  TF_R(17) TF_R(29) TF_R(16) TF_R(24)  x0 += ks2; x1 += ks0 + 2u;
  TF_R(13) TF_R(15) TF_R(26) TF_R(6)   x0 += ks0; x1 += ks1 + 3u;
  TF_R(17) TF_R(29) TF_R(16) TF_R(24)  x0 += ks1; x1 += ks2 + 4u;
  TF_R(13) TF_R(15) TF_R(26) TF_R(6)   x0 += ks2; x1 += ks0 + 5u;
#undef TF_R
#undef TF_ROT
}

__device__ inline double bf2d(unsigned short b) {
  return (double)__uint_as_float(((uint32_t)b) << 16);
}
__device__ inline unsigned short f2bf(float f) {  // RNE
  uint32_t u = __float_as_uint(f);
  u += 0x7FFFu + ((u >> 16) & 1u);
  return (unsigned short)(u >> 16);
}

// ---- prep body: dtype flag (ballot) + F table + b-major trace0 ----
// executed by blocks 0..63 (256 thr each); item idx = i*8+b
__device__ void prep_body(const void* __restrict__ X, uint8_t* __restrict__ ws) {
  __shared__ unsigned long long smask[4];
  __shared__ double sF[80];
  __shared__ int s_flag;
  const int tid = threadIdx.x;

  const uint32_t* xw = (const uint32_t*)X;
  uint32_t w = xw[tid];
  bool ok = (w == 0u || w == 0x3F800000u);
  unsigned long long m = __ballot(ok);
  if ((tid & 63) == 0) smask[tid >> 6] = m;

  if (tid < 80) {
    int tt = tid >> 3, b = tid & 7;
    const double PI = 3.14159265358979311599796346854;
    double arg = 0.5 * PI * log1p((double)tt) - 0.5 * PI * (double)b;
    arg = fmin(fmax(arg, -PI), PI);
    sF[tid] = 0.5 * (1.0 + cos(arg));
  }
  __syncthreads();
  if (tid == 0) {
    bool allbin = ((smask[0] & smask[1] & smask[2] & smask[3]) == ~0ull);
    s_flag = allbin ? 0 : 1;   // all exact {0.0f,1.0f} words -> f32 input
  }
  __syncthreads();
  const int flag = s_flag;

  if (blockIdx.x == 0) {
    if (tid == 0) *(uint32_t*)ws = (uint32_t)flag;
    if (tid < 80) ((double*)(ws + WS_F_OFF))[tid] = sF[tid];
  }

  const int idx = blockIdx.x * 256 + tid;   // 0..16383
  const int i = idx >> 3, b = idx & 7;
  double acc = 0.0;
  if (flag) {
    const unsigned short* Xb = (const unsigned short*)X;
    #pragma unroll
    for (int t = 0; t < 10; ++t) acc += bf2d(Xb[i * 10 + (9 - t)]) * sF[t * 8 + b];
  } else {
    const float* Xf = (const float*)X;
    #pragma unroll
    for (int t = 0; t < 10; ++t) acc += (double)Xf[i * 10 + (9 - t)] * sF[t * 8 + b];
  }
  ((double*)(ws + WS_TRACE0_OFF))[b * 2048 + i] = acc;   // b-major store
}

// ---- layer body: 2 rows/block, 2 waves/row, shfl + tiny-LDS reduce ----
// requires grid 1024 x 256
__device__ void layer_body(
    const void* __restrict__ W, const void* __restrict__ bias,
    const uint8_t* __restrict__ ws,
    int traceMode,                 // 0: full trace0 (b-major), 1: rank-1
    const double* __restrict__ sPrev,
    double* __restrict__ sOutD,    // may be null
    uint32_t key0, uint32_t key1,
    void* __restrict__ out, int pOff, int sOff)
{
  const uint32_t flag = *(const uint32_t*)ws;
  const double* F = (const double*)(ws + WS_F_OFF);
  const double* trT = (const double*)(ws + WS_TRACE0_OFF);
  const int lane = threadIdx.x & 63;
  const int wid  = threadIdx.x >> 6;          // 0..3
  const int row  = blockIdx.x * 2 + (wid >> 1);
  const int half = wid & 1;                   // which 1024-wide half of i
  const int ibase = half * 1024;

  double acc[8];
  #pragma unroll
  for (int b = 0; b < 8; ++b) acc[b] = 0.0;

  if (traceMode == 0) {
    if (flag) {
      const unsigned short* Wr = (const unsigned short*)W + (size_t)row * 16384;
      #pragma unroll 4
      for (int s = 0; s < 16; ++s) {
        int i = ibase + s * 64 + lane;
        uint4 v = *(const uint4*)(Wr + i * 8);
        acc[0] += bf2d((unsigned short)(v.x & 0xFFFFu)) * trT[0 * 2048 + i];
        acc[1] += bf2d((unsigned short)(v.x >> 16))     * trT[1 * 2048 + i];
        acc[2] += bf2d((unsigned short)(v.y & 0xFFFFu)) * trT[2 * 2048 + i];
        acc[3] += bf2d((unsigned short)(v.y >> 16))     * trT[3 * 2048 + i];
        acc[4] += bf2d((unsigned short)(v.z & 0xFFFFu)) * trT[4 * 2048 + i];
        acc[5] += bf2d((unsigned short)(v.z >> 16))     * trT[5 * 2048 + i];
        acc[6] += bf2d((unsigned short)(v.w & 0xFFFFu)) * trT[6 * 2048 + i];
        acc[7] += bf2d((unsigned short)(v.w >> 16))     * trT[7 * 2048 + i];
      }
    } else {
      const float* Wr = (const float*)W + (size_t)row * 16384;
      #pragma unroll 4
      for (int s = 0; s < 16; ++s) {
        int i = ibase + s * 64 + lane;
        float4 a = *(const float4*)(Wr + i * 8);
        float4 c = *(const float4*)(Wr + i * 8 + 4);
        acc[0] += (double)a.x * trT[0 * 2048 + i];
        acc[1] += (double)a.y * trT[1 * 2048 + i];
        acc[2] += (double)a.z * trT[2 * 2048 + i];
        acc[3] += (double)a.w * trT[3 * 2048 + i];
        acc[4] += (double)c.x * trT[4 * 2048 + i];
        acc[5] += (double)c.y * trT[5 * 2048 + i];
        acc[6] += (double)c.z * trT[6 * 2048 + i];
        acc[7] += (double)c.w * trT[7 * 2048 + i];
      }
    }
  } else {
    double F0[8];
    #pragma unroll
    for (int b = 0; b < 8; ++b) F0[b] = F[b];
    if (flag) {
      const unsigned short* Wr = (const unsigned short*)W + (size_t)row * 16384;
      #pragma unroll 4
      for (int s = 0; s < 16; ++s) {
        int i = ibase + s * 64 + lane;
        uint4 v = *(const uint4*)(Wr + i * 8);
        double si = sPrev[i];
        acc[0] += (bf2d((unsigned short)(v.x & 0xFFFFu)) * F0[0]) * si;
        acc[1] += (bf2d((unsigned short)(v.x >> 16))     * F0[1]) * si;
        acc[2] += (bf2d((unsigned short)(v.y & 0xFFFFu)) * F0[2]) * si;
        acc[3] += (bf2d((unsigned short)(v.y >> 16))     * F0[3]) * si;
        acc[4] += (bf2d((unsigned short)(v.z & 0xFFFFu)) * F0[4]) * si;
        acc[5] += (bf2d((unsigned short)(v.z >> 16))     * F0[5]) * si;
        acc[6] += (bf2d((unsigned short)(v.w & 0xFFFFu)) * F0[6]) * si;
        acc[7] += (bf2d((unsigned short)(v.w >> 16))     * F0[7]) * si;
      }
    } else {
      const float* Wr = (const float*)W + (size_t)row * 16384;
      #pragma unroll 4
      for (int s = 0; s < 16; ++s) {
        int i = ibase + s * 64 + lane;
        float4 a = *(const float4*)(Wr + i * 8);
        float4 c = *(const float4*)(Wr + i * 8 + 4);
        double si = sPrev[i];
        acc[0] += ((double)a.x * F0[0]) * si;
        acc[1] += ((double)a.y * F0[1]) * si;
        acc[2] += ((double)a.z * F0[2]) * si;
        acc[3] += ((double)a.w * F0[3]) * si;
        acc[4] += ((double)c.x * F0[4]) * si;
        acc[5] += ((double)c.y * F0[5]) * si;
        acc[6] += ((double)c.z * F0[6]) * si;
        acc[7] += ((double)c.w * F0[7]) * si;
      }
    }
  }

  double r = ((acc[0] + acc[1]) + (acc[2] + acc[3])) +
             ((acc[4] + acc[5]) + (acc[6] + acc[7]));
  #pragma unroll
  for (int off = 32; off > 0; off >>= 1) r += __shfl_down(r, off, 64);

  __shared__ double sred[4];
  if (lane == 0) sred[wid] = r;
  __syncthreads();

  if (threadIdx.x < 2) {
    const int o = blockIdx.x * 2 + threadIdx.x;        // this thread's row
    double rr = sred[2 * threadIdx.x] + sred[2 * threadIdx.x + 1];
    double bb = flag ? bf2d(((const unsigned short*)bias)[o])
                     : (double)((const float*)bias)[o];
    double x = rr + bb;
    double p = 1.0 / (1.0 + exp(-x));
    // JAX partitionable counter-mode uniform: element o -> block x=(0,o)
    uint32_t x0 = 0u, x1 = (uint32_t)o;
    tf2x32(key0, key1, x0, x1);
    uint32_t wbits = x0 ^ x1;
    float u = __uint_as_float((wbits >> 9) | 0x3F800000u) - 1.0f;
    double sp = ((double)u < p) ? 1.0 : 0.0;
    if (flag) {
      unsigned short* ob = (unsigned short*)out;
      ob[pOff + o] = f2bf((float)p);
      ob[sOff + o] = f2bf((float)sp);
    } else {
      float* of = (float*)out;
      of[pOff + o] = (float)p;
      of[sOff + o] = (float)sp;
    }
    if (sOutD) sOutD[o] = sp;
  }
  __syncthreads();   // protect sred reuse across phases
}

// ---- fused cooperative kernel: prep + 3 layers, grid 1024 x 256 ----
// __launch_bounds__(256,4): 4 waves/EU -> 4 blocks/CU -> 1024 blocks co-resident
__global__ __launch_bounds__(256, 4) void snn_fused(
    const void* __restrict__ X,
    const void* __restrict__ W0, const void* __restrict__ B0,
    const void* __restrict__ W1, const void* __restrict__ B1,
    const void* __restrict__ W2, const void* __restrict__ B2,
    uint8_t* __restrict__ ws,
    uint32_t k0a, uint32_t k0b, uint32_t k1a, uint32_t k1b,
    uint32_t k2a, uint32_t k2b,
    void* __restrict__ out)
{
  cg::grid_group grid = cg::this_grid();
  double* s0d = (double*)(ws + WS_S0_OFF);
  double* s1d = (double*)(ws + WS_S1_OFF);

  if (blockIdx.x < 64) prep_body(X, ws);
  __threadfence();
  grid.sync();

  layer_body(W0, B0, ws, 0, nullptr, s0d, k0a, k0b, out, 4096, 8192);
  __threadfence();
  grid.sync();

  layer_body(W1, B1, ws, 1, s0d, s1d, k1a, k1b, out, 6144, 10240);
  __threadfence();
  grid.sync();

  layer_body(W2, B2, ws, 1, s1d, nullptr, k2a, k2b, out, 0, 2048);
}

// ---- standalone fallback kernels (if cooperative launch is rejected) ----
__global__ __launch_bounds__(256) void snn_prep_kernel(
    const void* __restrict__ X, uint8_t* __restrict__ ws) {
  prep_body(X, ws);
}

__global__ __launch_bounds__(256) void snn_layer_kernel(
    const void* __restrict__ W, const void* __restrict__ bias,
    const uint8_t* __restrict__ ws, int traceMode,
    const double* __restrict__ sPrev, double* __restrict__ sOutD,
    uint32_t key0, uint32_t key1,
    void* __restrict__ out, int pOff, int sOff) {
  layer_body(W, bias, ws, traceMode, sPrev, sOutD, key0, key1, out, pOff, sOff);
}

extern "C" void kernel_launch(void* const* d_in, const int* in_sizes, int n_in,
                              void* d_out, int out_size, void* d_ws, size_t ws_size,
                              hipStream_t stream) {
  // keys: split(key(42), 3): k_i = threefry2x32((0,42), x=(0,i))
  uint32_t k0a = 0u, k0b = 0u;  tf2x32(0u, 42u, k0a, k0b);
  uint32_t k1a = 0u, k1b = 1u;  tf2x32(0u, 42u, k1a, k1b);
  uint32_t k2a = 0u, k2b = 2u;  tf2x32(0u, 42u, k2a, k2b);

  uint8_t* ws = (uint8_t*)d_ws;
  double* s0d = (double*)(ws + WS_S0_OFF);
  double* s1d = (double*)(ws + WS_S1_OFF);

  const void* X  = d_in[0];
  const void* W0 = d_in[1]; const void* B0 = d_in[3];
  const void* W1 = d_in[4]; const void* B1 = d_in[6];
  const void* W2 = d_in[7]; const void* B2 = d_in[9];
  void* outp = d_out;

  void* kargs[] = { (void*)&X, (void*)&W0, (void*)&B0, (void*)&W1, (void*)&B1,
                    (void*)&W2, (void*)&B2, (void*)&ws,
                    (void*)&k0a, (void*)&k0b, (void*)&k1a, (void*)&k1b,
                    (void*)&k2a, (void*)&k2b, (void*)&outp };

  hipError_t e = hipLaunchCooperativeKernel((const void*)snn_fused,
                                            dim3(1024), dim3(256),
                                            kargs, 0, stream);
  if (e != hipSuccess) {
    (void)hipGetLastError();   // clear sticky error, fall back to 4 launches
    snn_prep_kernel<<<64, 256, 0, stream>>>(X, ws);
    snn_layer_kernel<<<1024, 256, 0, stream>>>(W0, B0, ws, 0, nullptr, s0d,
                                               k0a, k0b, d_out, 4096, 8192);
    snn_layer_kernel<<<1024, 256, 0, stream>>>(W1, B1, ws, 1, s0d, s1d,
                                               k1a, k1b, d_out, 6144, 10240);
    snn_layer_kernel<<<1024, 256, 0, stream>>>(W2, B2, ws, 1, s1d, nullptr,
                                               k2a, k2b, d_out, 0, 2048);
  }
}

// Round 3
// 389.023 us; speedup vs baseline: 2.5159x; 2.5159x over previous
//
#include <hip/hip_runtime.h>
#include <hip/hip_bf16.h>
#include <stdint.h>
#include <stddef.h>

// ---------------- workspace layout (bytes) ----------------
// 0      : uint32 flag (0 = f32 inputs, 1 = bf16 inputs)
// 64     : double F[80]           (FF_FILT[t,b] = F[t*8+b], f64)
// 768    : double cTab0[2048*8]   (layer-0 coeffs = trace, i-major)
// 131840 : double cTab1[2048*8]   (layer-1 coeffs = F0[b]*s0_i)
// 262912 : double cTab2[2048*8]   (layer-2 coeffs = F0[b]*s1_i)
// 394240 : double partial[32*2048] (per-(igroup,row) f64 partials, 512 KB)
#define WS_F_OFF   64
#define WS_CT0     768
#define WS_CT1     131840
#define WS_CT2     262912
#define WS_PART    394240

// ---------------- threefry2x32 (JAX-exact, 20 rounds) ----------------
__host__ __device__ inline void tf2x32(uint32_t k0, uint32_t k1,
                                       uint32_t& x0, uint32_t& x1) {
  uint32_t ks0 = k0, ks1 = k1, ks2 = k0 ^ k1 ^ 0x1BD11BDAu;
  x0 += ks0; x1 += ks1;
#define TF_ROT(v, n) (((v) << (n)) | ((v) >> (32 - (n))))
#define TF_R(r) { x0 += x1; x1 = TF_ROT(x1, r); x1 ^= x0; }
  TF_R(13) TF_R(15) TF_R(26) TF_R(6)   x0 += ks1; x1 += ks2 + 1u;
  TF_R(17) TF_R(29) TF_R(16) TF_R(24)  x0 += ks2; x1 += ks0 + 2u;
  TF_R(13) TF_R(15) TF_R(26) TF_R(6)   x0 += ks0; x1 += ks1 + 3u;
  TF_R(17) TF_R(29) TF_R(16) TF_R(24)  x0 += ks1; x1 += ks2 + 4u;
  TF_R(13) TF_R(15) TF_R(26) TF_R(6)   x0 += ks2; x1 += ks0 + 5u;
#undef TF_R
#undef TF_ROT
}

__device__ inline double bf2d(unsigned short b) {
  return (double)__uint_as_float(((uint32_t)b) << 16);
}
__device__ inline unsigned short f2bf(float f) {  // RNE
  uint32_t u = __float_as_uint(f);
  u += 0x7FFFu + ((u >> 16) & 1u);
  return (unsigned short)(u >> 16);
}

__device__ inline double wred64(double r) {       // 64-lane sum, lane0 valid
  #pragma unroll
  for (int off = 32; off > 0; off >>= 1) r += __shfl_down(r, off, 64);
  return r;
}

// ---- prep: dtype flag (ballot) + F table + i-major trace0 (cTab0) ----
// grid 64 x 256; item idx = i*8+b
__global__ __launch_bounds__(256) void snn_prep_kernel(
    const void* __restrict__ X, uint8_t* __restrict__ ws) {
  __shared__ unsigned long long smask[4];
  __shared__ double sF[80];
  __shared__ int s_flag;
  const int tid = threadIdx.x;

  const uint32_t* xw = (const uint32_t*)X;
  uint32_t w = xw[tid];
  bool ok = (w == 0u || w == 0x3F800000u);
  unsigned long long m = __ballot(ok);
  if ((tid & 63) == 0) smask[tid >> 6] = m;

  if (tid < 80) {
    int tt = tid >> 3, b = tid & 7;
    const double PI = 3.14159265358979311599796346854;
    double arg = 0.5 * PI * log1p((double)tt) - 0.5 * PI * (double)b;
    arg = fmin(fmax(arg, -PI), PI);
    sF[tid] = 0.5 * (1.0 + cos(arg));
  }
  __syncthreads();
  if (tid == 0) {
    bool allbin = ((smask[0] & smask[1] & smask[2] & smask[3]) == ~0ull);
    s_flag = allbin ? 0 : 1;   // all exact {0.0f,1.0f} words -> f32 input
  }
  __syncthreads();
  const int flag = s_flag;

  if (blockIdx.x == 0) {
    if (tid == 0) *(uint32_t*)ws = (uint32_t)flag;
    if (tid < 80) ((double*)(ws + WS_F_OFF))[tid] = sF[tid];
  }

  const int idx = blockIdx.x * 256 + tid;   // 0..16383 = i*8+b
  const int i = idx >> 3, b = idx & 7;
  double acc = 0.0;
  if (flag) {
    const unsigned short* Xb = (const unsigned short*)X;
    #pragma unroll
    for (int t = 0; t < 10; ++t) acc += bf2d(Xb[i * 10 + (9 - t)]) * sF[t * 8 + b];
  } else {
    const float* Xf = (const float*)X;
    #pragma unroll
    for (int t = 0; t < 10; ++t) acc += (double)Xf[i * 10 + (9 - t)] * sF[t * 8 + b];
  }
  ((double*)(ws + WS_CT0))[idx] = acc;   // i-major
}

// ---- accumulate: lane<->i, c8 in registers, weight-only hot loop ----
// grid 1024 x 256 (4 independent waves/block, no LDS, no syncthreads).
// wave wg = blockIdx*4+wid: ig = wg&31 (64-i group), rc = wg>>5 (16-row chunk).
// Hot loop per row: 2 coalesced dwordx4 (wave reads 2048B contiguous), 8 f64
// FMA, 6-step shfl reduce, one 8B store. No other VMEM -> progressive vmcnt,
// deep compiler pipelining of the weight stream.
__global__ __launch_bounds__(256) void snn_acc_kernel(
    const void* __restrict__ W, const uint8_t* __restrict__ ws,
    const double* __restrict__ cTab, double* __restrict__ partial)
{
  const uint32_t flag = *(const uint32_t*)ws;
  const int lane = threadIdx.x & 63;
  const int wid  = threadIdx.x >> 6;
  const int wg   = blockIdx.x * 4 + wid;   // 0..4095
  const int ig   = wg & 31;                // i-group
  const int rc   = wg >> 5;                // row chunk 0..127
  const int i    = ig * 64 + lane;
  const int row0 = rc * 16;

  double c8[8];
  {
    const double* cp = cTab + (size_t)i * 8;
    #pragma unroll
    for (int b = 0; b < 8; ++b) c8[b] = cp[b];
  }

  if (flag) {
    const unsigned short* base =
        (const unsigned short*)W + (size_t)row0 * 16384 + (size_t)i * 8;
    for (int rr = 0; rr < 16; rr += 4) {
      uint4 v0 = *(const uint4*)(base + (size_t)(rr + 0) * 16384);
      uint4 v1 = *(const uint4*)(base + (size_t)(rr + 1) * 16384);
      uint4 v2 = *(const uint4*)(base + (size_t)(rr + 2) * 16384);
      uint4 v3 = *(const uint4*)(base + (size_t)(rr + 3) * 16384);
      #pragma unroll
      for (int k = 0; k < 4; ++k) {
        uint4 v = (k == 0) ? v0 : (k == 1) ? v1 : (k == 2) ? v2 : v3;
        double t0 = bf2d((unsigned short)(v.x & 0xFFFFu)) * c8[0];
        double t1 = bf2d((unsigned short)(v.x >> 16))     * c8[1];
        double t2 = bf2d((unsigned short)(v.y & 0xFFFFu)) * c8[2];
        double t3 = bf2d((unsigned short)(v.y >> 16))     * c8[3];
        double t4 = bf2d((unsigned short)(v.z & 0xFFFFu)) * c8[4];
        double t5 = bf2d((unsigned short)(v.z >> 16))     * c8[5];
        double t6 = bf2d((unsigned short)(v.w & 0xFFFFu)) * c8[6];
        double t7 = bf2d((unsigned short)(v.w >> 16))     * c8[7];
        double r = ((t0 + t1) + (t2 + t3)) + ((t4 + t5) + (t6 + t7));
        r = wred64(r);
        if (lane == 0) partial[(size_t)ig * 2048 + row0 + rr + k] = r;
      }
    }
  } else {
    const float* base =
        (const float*)W + (size_t)row0 * 16384 + (size_t)i * 8;
    for (int rr = 0; rr < 16; rr += 4) {
      float4 a0 = *(const float4*)(base + (size_t)(rr + 0) * 16384);
      float4 c0 = *(const float4*)(base + (size_t)(rr + 0) * 16384 + 4);
      float4 a1 = *(const float4*)(base + (size_t)(rr + 1) * 16384);
      float4 c1 = *(const float4*)(base + (size_t)(rr + 1) * 16384 + 4);
      float4 a2 = *(const float4*)(base + (size_t)(rr + 2) * 16384);
      float4 c2 = *(const float4*)(base + (size_t)(rr + 2) * 16384 + 4);
      float4 a3 = *(const float4*)(base + (size_t)(rr + 3) * 16384);
      float4 c3 = *(const float4*)(base + (size_t)(rr + 3) * 16384 + 4);
      #pragma unroll
      for (int k = 0; k < 4; ++k) {
        float4 a = (k == 0) ? a0 : (k == 1) ? a1 : (k == 2) ? a2 : a3;
        float4 c = (k == 0) ? c0 : (k == 1) ? c1 : (k == 2) ? c2 : c3;
        double t0 = (double)a.x * c8[0];
        double t1 = (double)a.y * c8[1];
        double t2 = (double)a.z * c8[2];
        double t3 = (double)a.w * c8[3];
        double t4 = (double)c.x * c8[4];
        double t5 = (double)c.y * c8[5];
        double t6 = (double)c.z * c8[6];
        double t7 = (double)c.w * c8[7];
        double r = ((t0 + t1) + (t2 + t3)) + ((t4 + t5) + (t6 + t7));
        r = wred64(r);
        if (lane == 0) partial[(size_t)ig * 2048 + row0 + rr + k] = r;
      }
    }
  }
}

// ---- finalize: deterministic 32-way partial sum + bias + sigmoid + RNG ----
// grid 8 x 256 (one thread per output row). Also builds next layer's cTab:
// c8next[o][b] = F0[b] * spike_o  (exact: spike in {0,1}).
__global__ __launch_bounds__(256) void snn_fin_kernel(
    const uint8_t* __restrict__ ws, const double* __restrict__ partial,
    const void* __restrict__ bias,
    double* __restrict__ cNext,      // may be null (last layer)
    uint32_t key0, uint32_t key1,
    void* __restrict__ out, int pOff, int sOff)
{
  const uint32_t flag = *(const uint32_t*)ws;
  const double* F = (const double*)(ws + WS_F_OFF);
  const int o = blockIdx.x * 256 + threadIdx.x;   // 0..2047

  double r = 0.0;
  #pragma unroll 8
  for (int ig = 0; ig < 32; ++ig) r += partial[(size_t)ig * 2048 + o];

  double bb = flag ? bf2d(((const unsigned short*)bias)[o])
                   : (double)((const float*)bias)[o];
  double x = r + bb;
  double p = 1.0 / (1.0 + exp(-x));
  // JAX partitionable counter-mode uniform: element o -> block x=(0,o)
  uint32_t x0 = 0u, x1 = (uint32_t)o;
  tf2x32(key0, key1, x0, x1);
  uint32_t wbits = x0 ^ x1;
  float u = __uint_as_float((wbits >> 9) | 0x3F800000u) - 1.0f;
  double sp = ((double)u < p) ? 1.0 : 0.0;

  if (flag) {
    unsigned short* ob = (unsigned short*)out;
    ob[pOff + o] = f2bf((float)p);
    ob[sOff + o] = f2bf((float)sp);
  } else {
    float* of = (float*)out;
    of[pOff + o] = (float)p;
    of[sOff + o] = (float)sp;
  }
  if (cNext) {
    double* cp = cNext + (size_t)o * 8;
    #pragma unroll
    for (int b = 0; b < 8; ++b) cp[b] = F[b] * sp;   // exact for sp in {0,1}
  }
}

extern "C" void kernel_launch(void* const* d_in, const int* in_sizes, int n_in,
                              void* d_out, int out_size, void* d_ws, size_t ws_size,
                              hipStream_t stream) {
  // keys: split(key(42), 3): k_i = threefry2x32((0,42), x=(0,i))
  uint32_t k0a = 0u, k0b = 0u;  tf2x32(0u, 42u, k0a, k0b);
  uint32_t k1a = 0u, k1b = 1u;  tf2x32(0u, 42u, k1a, k1b);
  uint32_t k2a = 0u, k2b = 2u;  tf2x32(0u, 42u, k2a, k2b);

  uint8_t* ws = (uint8_t*)d_ws;
  double* ct0  = (double*)(ws + WS_CT0);
  double* ct1  = (double*)(ws + WS_CT1);
  double* ct2  = (double*)(ws + WS_CT2);
  double* part = (double*)(ws + WS_PART);

  const void* X  = d_in[0];
  const void* W0 = d_in[1]; const void* B0 = d_in[3];
  const void* W1 = d_in[4]; const void* B1 = d_in[6];
  const void* W2 = d_in[7]; const void* B2 = d_in[9];

  snn_prep_kernel<<<64, 256, 0, stream>>>(X, ws);

  // layer 0: p0 -> out[4096..], s0 -> out[8192..]; builds cTab1
  snn_acc_kernel<<<1024, 256, 0, stream>>>(W0, ws, ct0, part);
  snn_fin_kernel<<<8, 256, 0, stream>>>(ws, part, B0, ct1,
                                        k0a, k0b, d_out, 4096, 8192);
  // layer 1: p1 -> out[6144..], s1 -> out[10240..]; builds cTab2
  snn_acc_kernel<<<1024, 256, 0, stream>>>(W1, ws, ct1, part);
  snn_fin_kernel<<<8, 256, 0, stream>>>(ws, part, B1, ct2,
                                        k1a, k1b, d_out, 6144, 10240);
  // layer 2: p2 -> out[0..], s2 -> out[2048..]
  snn_acc_kernel<<<1024, 256, 0, stream>>>(W2, ws, ct2, part);
  snn_fin_kernel<<<8, 256, 0, stream>>>(ws, part, B2, nullptr,
                                        k2a, k2b, d_out, 0, 2048);
}